// Round 5
// baseline (1893.504 us; speedup 1.0000x reference)
//
#include <hip/hip_runtime.h>
#include <math.h>

#define TT 512
#define DD 128
#define MM 512
#define EE 512
#define NTAGS 74
#define GH 64
#define LH 256

typedef _Float16 half_t;
typedef _Float16 v2h __attribute__((ext_vector_type(2)));
typedef _Float16 v8h __attribute__((ext_vector_type(8)));
typedef _Float16 v16h __attribute__((ext_vector_type(16)));

__device__ __forceinline__ float fdot2f(v2h a, v2h b, float c) {
#if __has_builtin(__builtin_amdgcn_fdot2)
    return __builtin_amdgcn_fdot2(a, b, c, false);
#else
    return c + (float)a[0] * (float)b[0] + (float)a[1] * (float)b[1];
#endif
}

__device__ __forceinline__ float sigf(float x) { return 1.f / (1.f + __expf(-x)); }
__device__ __forceinline__ float tanhfast(float x) { return 1.f - 2.f / (__expf(2.f * x) + 1.f); }

// 16 f32 -> v16h (SSA value, 8 VGPRs)
__device__ __forceinline__ v16h load16(const float* p) {
    float4 x0 = ((const float4*)p)[0];
    float4 x1 = ((const float4*)p)[1];
    float4 x2 = ((const float4*)p)[2];
    float4 x3 = ((const float4*)p)[3];
    v16h r;
    r[0] = (half_t)x0.x; r[1] = (half_t)x0.y; r[2] = (half_t)x0.z; r[3] = (half_t)x0.w;
    r[4] = (half_t)x1.x; r[5] = (half_t)x1.y; r[6] = (half_t)x1.z; r[7] = (half_t)x1.w;
    r[8] = (half_t)x2.x; r[9] = (half_t)x2.y; r[10] = (half_t)x2.z; r[11] = (half_t)x2.w;
    r[12] = (half_t)x3.x; r[13] = (half_t)x3.y; r[14] = (half_t)x3.z; r[15] = (half_t)x3.w;
    return r;
}

// Opacity barrier: values redefined by asm cannot be rematerialized from
// memory by the backend (defeats load-sinking under occupancy pressure).
#define OPAQUE4(a, b, c, d) \
    asm volatile("" : "+v"(a), "+v"(b), "+v"(c), "+v"(d))
#define OPAQUE6(a, b, c, d, e, f) \
    asm volatile("" : "+v"(a), "+v"(b), "+v"(c), "+v"(d), "+v"(e), "+v"(f))

__device__ __forceinline__ void dot8(const v8h& w, const v8h& h, float& x0, float& x1) {
    x0 = fdot2f(v2h{w[0], w[1]}, v2h{h[0], h[1]}, x0);
    x1 = fdot2f(v2h{w[2], w[3]}, v2h{h[2], h[3]}, x1);
    x0 = fdot2f(v2h{w[4], w[5]}, v2h{h[4], h[5]}, x0);
    x1 = fdot2f(v2h{w[6], w[7]}, v2h{h[6], h[7]}, x1);
}

__device__ __forceinline__ void dot16(const v16h& w, const v8h& h0, const v8h& h1,
                                      float& x0, float& x1) {
    x0 = fdot2f(v2h{w[0], w[1]}, v2h{h0[0], h0[1]}, x0);
    x1 = fdot2f(v2h{w[2], w[3]}, v2h{h0[2], h0[3]}, x1);
    x0 = fdot2f(v2h{w[4], w[5]}, v2h{h0[4], h0[5]}, x0);
    x1 = fdot2f(v2h{w[6], w[7]}, v2h{h0[6], h0[7]}, x1);
    x0 = fdot2f(v2h{w[8], w[9]}, v2h{h1[0], h1[1]}, x0);
    x1 = fdot2f(v2h{w[10], w[11]}, v2h{h1[2], h1[3]}, x1);
    x0 = fdot2f(v2h{w[12], w[13]}, v2h{h1[4], h1[5]}, x0);
    x1 = fdot2f(v2h{w[14], w[15]}, v2h{h1[6], h1[7]}, x1);
}

// ---------------- K1: dots[m] = <memory[m], u> ----------------
__global__ __launch_bounds__(256) void k_dots(const float* __restrict__ mem,
                                              const float* __restrict__ u,
                                              float* __restrict__ dots) {
    int m = blockIdx.x;
    const float4* m4 = (const float4*)(mem + (size_t)m * TT * DD);
    const float4* u4 = (const float4*)u;
    float acc = 0.f;
#pragma unroll 4
    for (int it = 0; it < (TT * DD / 4) / 256; ++it) {
        int i = it * 256 + threadIdx.x;
        float4 a = m4[i], b = u4[i];
        acc += a.x * b.x + a.y * b.y + a.z * b.z + a.w * b.w;
    }
    for (int off = 32; off; off >>= 1) acc += __shfl_down(acc, off, 64);
    __shared__ float red[4];
    int w = threadIdx.x >> 6, l = threadIdx.x & 63;
    if (l == 0) red[w] = acc;
    __syncthreads();
    if (threadIdx.x == 0) dots[m] = red[0] + red[1] + red[2] + red[3];
}

// ---------------- K2: p = softmax(dots) ----------------
__global__ __launch_bounds__(512) void k_softmax_p(const float* __restrict__ dots,
                                                   float* __restrict__ p) {
    int tid = threadIdx.x;
    float v = dots[tid];
    float mx = v;
    for (int off = 32; off; off >>= 1) mx = fmaxf(mx, __shfl_down(mx, off, 64));
    __shared__ float red[8];
    __shared__ float bm, bs;
    int w = tid >> 6, l = tid & 63;
    if (l == 0) red[w] = mx;
    __syncthreads();
    if (tid == 0) {
        float t = red[0];
        for (int i = 1; i < 8; ++i) t = fmaxf(t, red[i]);
        bm = t;
    }
    __syncthreads();
    float e = __expf(v - bm);
    float sm = e;
    for (int off = 32; off; off >>= 1) sm += __shfl_down(sm, off, 64);
    if (l == 0) red[w] = sm;
    __syncthreads();
    if (tid == 0) {
        float t = 0.f;
        for (int i = 0; i < 8; ++i) t += red[i];
        bs = t;
    }
    __syncthreads();
    p[tid] = e / bs;
}

// ---------------- K3: Mbar = sum_m p[m]*memory[m] ----------------
__global__ __launch_bounds__(128) void k_wsum(const float* __restrict__ mem,
                                              const float* __restrict__ p,
                                              float* __restrict__ Mbar) {
    __shared__ float pl[MM];
    for (int i = threadIdx.x; i < MM; i += 128) pl[i] = p[i];
    __syncthreads();
    int i4 = blockIdx.x * 128 + threadIdx.x;
    const float4* m4 = (const float4*)mem;
    float4 acc = {0.f, 0.f, 0.f, 0.f};
#pragma unroll 4
    for (int m = 0; m < MM; ++m) {
        float pm = pl[m];
        float4 a = m4[(size_t)m * (TT * DD / 4) + i4];
        acc.x += pm * a.x; acc.y += pm * a.y; acc.z += pm * a.z; acc.w += pm * a.w;
    }
    ((float4*)Mbar)[i4] = acc;
}

// ---------------- K4: G = Mbar@W1.T + u@W2.T + b_ff ----------------
__global__ __launch_bounds__(128) void k_G(const float* __restrict__ Mbar,
                                           const float* __restrict__ u,
                                           const float* __restrict__ Wff,
                                           const float* __restrict__ bff,
                                           float* __restrict__ G) {
    int t = blockIdx.x, d = threadIdx.x;
    __shared__ __align__(16) float Ml[DD], ul[DD];
    Ml[d] = Mbar[t * DD + d];
    ul[d] = u[t * DD + d];
    __syncthreads();
    const float* wr = Wff + (size_t)d * 2 * DD;
    float a0 = 0.f, a1 = 0.f;
#pragma unroll 4
    for (int k = 0; k < DD; ++k) {
        a0 += Ml[k] * wr[k];
        a1 += ul[k] * wr[DD + k];
    }
    G[t * DD + d] = a0 + a1 + bff[d];
}

// ---------------- K5: GRU input projections ----------------
__global__ __launch_bounds__(384) void k_gru_gi(const float* __restrict__ G,
                                                const float* __restrict__ Wf,
                                                const float* __restrict__ bf,
                                                const float* __restrict__ Wb,
                                                const float* __restrict__ bb,
                                                float* __restrict__ gi) {
    int t = blockIdx.x;
    __shared__ __align__(16) float Gl[DD];
    if (threadIdx.x < DD) Gl[threadIdx.x] = G[t * DD + threadIdx.x];
    __syncthreads();
    int r = threadIdx.x;
    const float* w;
    float b;
    float* o;
    if (r < 192) {
        w = Wf + (size_t)r * DD; b = bf[r]; o = gi + ((size_t)0 * TT + t) * 192 + r;
    } else {
        int rr = r - 192;
        w = Wb + (size_t)rr * DD; b = bb[rr]; o = gi + ((size_t)1 * TT + t) * 192 + rr;
    }
    float a0 = 0.f, a1 = 0.f;
#pragma unroll 4
    for (int k = 0; k < DD; k += 2) {
        a0 += Gl[k] * w[k];
        a1 += Gl[k + 1] * w[k + 1];
    }
    *o = a0 + a1 + b;
}

// ---------------- K6: sequential BiGRU (2 blocks = 2 directions) ----------------
__global__ __attribute__((amdgpu_waves_per_eu(1, 2)))
__launch_bounds__(256) void k_gru_seq(const float* __restrict__ Whh_f,
                                      const float* __restrict__ bhh_f,
                                      const float* __restrict__ Whh_b,
                                      const float* __restrict__ bhh_b,
                                      const float* __restrict__ gi,
                                      float* __restrict__ hbuf) {
    int dir = blockIdx.x;
    int tid = threadIdx.x;
    const float* Whh = dir ? Whh_b : Whh_f;
    const float* bhh = dir ? bhh_b : bhh_f;
    v16h w0 = {}, w1 = {}, w2 = {}, w3 = {};
    float bh = 0.f;
    if (tid < 192) {
        const float* wr = Whh + (size_t)tid * 64;
        w0 = load16(wr);
        w1 = load16(wr + 16);
        w2 = load16(wr + 32);
        w3 = load16(wr + 48);
        bh = bhh[tid];
    }
    OPAQUE4(w0, w1, w2, w3);
    __shared__ __align__(16) half_t hl[64];
    __shared__ float pa[192];
    if (tid < 32) ((v2h*)hl)[tid] = v2h{(half_t)0.f, (half_t)0.f};
    float h = 0.f;
    __syncthreads();
    for (int s = 0; s < TT; ++s) {
        int t = dir ? (TT - 1 - s) : s;
        float g_r = 0.f, g_z = 0.f, g_n = 0.f;
        if (tid < 64) {  // prefetch gi early
            const float* git = gi + ((size_t)dir * TT + t) * 192;
            g_r = git[tid]; g_z = git[64 + tid]; g_n = git[128 + tid];
        }
        if (tid < 192) {
            float a0 = bh, a1 = 0.f;
            v8h h0, h1;
            h0 = *(const v8h*)(hl + 0);  h1 = *(const v8h*)(hl + 8);
            dot16(w0, h0, h1, a0, a1);
            h0 = *(const v8h*)(hl + 16); h1 = *(const v8h*)(hl + 24);
            dot16(w1, h0, h1, a0, a1);
            h0 = *(const v8h*)(hl + 32); h1 = *(const v8h*)(hl + 40);
            dot16(w2, h0, h1, a0, a1);
            h0 = *(const v8h*)(hl + 48); h1 = *(const v8h*)(hl + 56);
            dot16(w3, h0, h1, a0, a1);
            pa[tid] = a0 + a1;
        }
        __syncthreads();
        if (tid < 64) {
            float r = sigf(g_r + pa[tid]);
            float z = sigf(g_z + pa[64 + tid]);
            float n = tanhfast(g_n + r * pa[128 + tid]);
            h = (1.f - z) * n + z * h;
            hbuf[t * DD + dir * 64 + tid] = h;
            hl[tid] = (half_t)h;
        }
        __syncthreads();
    }
}

// ---------------- K7: x = embed + (u + h)@W_k.T + b_k ----------------
__global__ __launch_bounds__(512) void k_x(const float* __restrict__ u,
                                           const float* __restrict__ hbuf,
                                           const float* __restrict__ Wk,
                                           const float* __restrict__ bk,
                                           const float* __restrict__ embed,
                                           float* __restrict__ x) {
    int t = blockIdx.x, e = threadIdx.x;
    __shared__ __align__(16) float sl[DD];
    if (e < DD) sl[e] = u[t * DD + e] + hbuf[t * DD + e];
    __syncthreads();
    const float* wr = Wk + (size_t)e * DD;
    float a0 = 0.f, a1 = 0.f;
#pragma unroll 4
    for (int k = 0; k < DD; k += 2) {
        a0 += sl[k] * wr[k];
        a1 += sl[k + 1] * wr[k + 1];
    }
    x[t * EE + e] = embed[t * EE + e] + a0 + a1 + bk[e];
}

// ---------------- K8: LSTM input projections, 8 timesteps per block ----------------
__global__ __launch_bounds__(1024) void k_lstm_gi(const float* __restrict__ x,
                                                  const float* __restrict__ Wf,
                                                  const float* __restrict__ bf,
                                                  const float* __restrict__ Wb,
                                                  const float* __restrict__ bb,
                                                  float* __restrict__ gi) {
    int dir = blockIdx.y;
    int t0 = blockIdx.x * 8;
    __shared__ __align__(16) float xl[8 * EE];
    for (int i = threadIdx.x; i < 8 * EE; i += 1024) xl[i] = x[(size_t)t0 * EE + i];
    __syncthreads();
    int r = threadIdx.x;
    const float* W = dir ? Wb : Wf;
    const float* bi = dir ? bb : bf;
    const float* wr = W + (size_t)r * EE;
    float b = bi[r];
    float acc[8];
#pragma unroll
    for (int uu = 0; uu < 8; ++uu) acc[uu] = b;
    for (int k = 0; k < EE; k += 4) {
        float4 wv = *(const float4*)(wr + k);
#pragma unroll
        for (int uu = 0; uu < 8; ++uu) {
            float4 xv = *(const float4*)(&xl[uu * EE + k]);
            acc[uu] += wv.x * xv.x + wv.y * xv.y + wv.z * xv.z + wv.w * xv.w;
        }
    }
#pragma unroll
    for (int uu = 0; uu < 8; ++uu)
        gi[((size_t)dir * TT + (t0 + uu)) * 1024 + r] = acc[uu];
}

// ---------------- K9: sequential BiLSTM, one WG per direction ----------------
// 512 threads, 2 gate rows/thread. Cols 0..191 as 24 named v16h = 192 VGPRs;
// cols 192..255 in LDS (128 KB). amdgpu_waves_per_eu(1,2) caps the backend's
// occupancy target at 2 waves/EU (256-VGPR budget) — R2-R4 showed the
// backend otherwise targets 4-8 waves/EU and remats the weight loads into
// the loop (~400-800 KB/CU/step reload). OPAQUE barriers kill remat.
__global__ __attribute__((amdgpu_waves_per_eu(1, 2)))
__launch_bounds__(512) void k_lstm_seq(const float* __restrict__ Whh_f,
                                       const float* __restrict__ bhh_f,
                                       const float* __restrict__ Whh_b,
                                       const float* __restrict__ bhh_b,
                                       const float* __restrict__ gi,
                                       float* __restrict__ comb) {
    int dir = blockIdx.x;
    int tid = threadIdx.x;
    int u = tid & 255;
    int hi = tid >> 8;               // 0 -> rows (i,g); 1 -> rows (f,o)
    int r0 = hi * 256 + u;           // gate i or f
    int r1 = 512 + hi * 256 + u;     // gate g or o
    const float* Whh = dir ? Whh_b : Whh_f;
    const float* bhh = dir ? bhh_b : bhh_f;

    __shared__ __align__(16) half_t wsl[8 * 1024 * 8];  // [chunk c][row][8 f16] = 128 KB
    __shared__ __align__(16) half_t hl[256];
    __shared__ float pa[1024];

    // Stage LDS weight slice: cols 192..255, chunk-major.
#pragma unroll
    for (int it = 0; it < 16; ++it) {
        int i = it * 512 + tid;  // [0, 8192)
        int row = i >> 3, c = i & 7;
        const float* src = Whh + (size_t)row * 256 + 192 + c * 8;
        float4 v0 = *(const float4*)(src);
        float4 v1 = *(const float4*)(src + 4);
        v8h hv;
        hv[0] = (half_t)v0.x; hv[1] = (half_t)v0.y; hv[2] = (half_t)v0.z; hv[3] = (half_t)v0.w;
        hv[4] = (half_t)v1.x; hv[5] = (half_t)v1.y; hv[6] = (half_t)v1.z; hv[7] = (half_t)v1.w;
        *(v8h*)(wsl + ((size_t)c * 1024 + row) * 8) = hv;
    }
    // Register weights: cols 0..191 of both rows, as named SSA vectors.
    const float* s0 = Whh + (size_t)r0 * 256;
    const float* s1 = Whh + (size_t)r1 * 256;
    v16h wa0 = load16(s0), wa1 = load16(s0 + 16), wa2 = load16(s0 + 32),
         wa3 = load16(s0 + 48), wa4 = load16(s0 + 64), wa5 = load16(s0 + 80),
         wa6 = load16(s0 + 96), wa7 = load16(s0 + 112), wa8 = load16(s0 + 128),
         wa9 = load16(s0 + 144), wa10 = load16(s0 + 160), wa11 = load16(s0 + 176);
    v16h wb0 = load16(s1), wb1 = load16(s1 + 16), wb2 = load16(s1 + 32),
         wb3 = load16(s1 + 48), wb4 = load16(s1 + 64), wb5 = load16(s1 + 80),
         wb6 = load16(s1 + 96), wb7 = load16(s1 + 112), wb8 = load16(s1 + 128),
         wb9 = load16(s1 + 144), wb10 = load16(s1 + 160), wb11 = load16(s1 + 176);
    OPAQUE6(wa0, wa1, wa2, wa3, wa4, wa5);
    OPAQUE6(wa6, wa7, wa8, wa9, wa10, wa11);
    OPAQUE6(wb0, wb1, wb2, wb3, wb4, wb5);
    OPAQUE6(wb6, wb7, wb8, wb9, wb10, wb11);
    float bh0 = bhh[r0], bh1 = bhh[r1];
    if (tid < 128) ((v2h*)hl)[tid] = v2h{(half_t)0.f, (half_t)0.f};
    float c_state = 0.f;
    __syncthreads();

    for (int s = 0; s < TT; ++s) {
        int t = dir ? (TT - 1 - s) : s;
        const float* gbase = gi + ((size_t)dir * TT + t) * 1024;
        float g0 = gbase[r0], g1 = gbase[r1];
        float a0 = bh0, a1 = 0.f, b0 = bh1, b1 = 0.f;
        v8h h0, h1;
#define DOTC(c)                                                  \
        h0 = *(const v8h*)(hl + 16 * (c));                       \
        h1 = *(const v8h*)(hl + 16 * (c) + 8);                   \
        dot16(wa##c, h0, h1, a0, a1);                            \
        dot16(wb##c, h0, h1, b0, b1);
        DOTC(0); DOTC(1); DOTC(2); DOTC(3); DOTC(4); DOTC(5);
        DOTC(6); DOTC(7); DOTC(8); DOTC(9); DOTC(10); DOTC(11);
#undef DOTC
        // LDS-resident cols 192..255.
#pragma unroll
        for (int c = 0; c < 8; ++c) {
            v8h hv = *(const v8h*)(hl + 192 + c * 8);
            v8h va = *(const v8h*)(wsl + ((size_t)c * 1024 + r0) * 8);
            v8h vb = *(const v8h*)(wsl + ((size_t)c * 1024 + r1) * 8);
            dot8(va, hv, a0, a1);
            dot8(vb, hv, b0, b1);
        }
        pa[r0] = a0 + a1 + g0;
        pa[r1] = b0 + b1 + g1;
        __syncthreads();
        if (tid < 256) {
            float iv = sigf(pa[tid]);
            float fv = sigf(pa[256 + tid]);
            float gv = tanhfast(pa[512 + tid]);
            float ov = sigf(pa[768 + tid]);
            c_state = fv * c_state + iv * gv;
            float h = ov * tanhfast(c_state);
            comb[(size_t)t * EE + dir * 256 + tid] = h;
            hl[tid] = (half_t)h;
        }
        __syncthreads();
    }
}

// ---------------- K10: logits + softmax ----------------
__global__ __launch_bounds__(128) void k_out(const float* __restrict__ comb,
                                             const float* __restrict__ Wout,
                                             const float* __restrict__ bout,
                                             float* __restrict__ out) {
    int t = blockIdx.x;
    __shared__ __align__(16) float cl[EE];
    __shared__ float ll[NTAGS];
    __shared__ float mred, sred;
    for (int i = threadIdx.x; i < EE; i += 128) cl[i] = comb[(size_t)t * EE + i];
    __syncthreads();
    int e = threadIdx.x;
    if (e < NTAGS) {
        const float* wr = Wout + (size_t)e * EE;
        float a0 = 0.f, a1 = 0.f;
#pragma unroll 4
        for (int k = 0; k < EE; k += 2) {
            a0 += cl[k] * wr[k];
            a1 += cl[k + 1] * wr[k + 1];
        }
        ll[e] = a0 + a1 + bout[e];
    }
    __syncthreads();
    if (threadIdx.x == 0) {
        float m = ll[0];
        for (int i = 1; i < NTAGS; ++i) m = fmaxf(m, ll[i]);
        float ss = 0.f;
        for (int i = 0; i < NTAGS; ++i) ss += __expf(ll[i] - m);
        mred = m;
        sred = ss;
    }
    __syncthreads();
    if (e < NTAGS) out[t * NTAGS + e] = __expf(ll[e] - mred) / sred;
}

// ---------------- workspace layout (floats) ----------------
#define OFF_DOTS  ((size_t)0)
#define OFF_P     ((size_t)512)
#define OFF_MBAR  ((size_t)1024)
#define OFF_G     ((size_t)66560)
#define OFF_GIG   ((size_t)132096)   // [2][512][192]
#define OFF_HBUF  ((size_t)328704)   // [512][128]
#define OFF_X     ((size_t)394240)   // [512][512]
#define OFF_GIL   ((size_t)656384)   // [2][512][1024]
#define OFF_COMB  ((size_t)1704960)  // [512][512]

extern "C" void kernel_launch(void* const* d_in, const int* in_sizes, int n_in,
                              void* d_out, int out_size, void* d_ws, size_t ws_size,
                              hipStream_t stream) {
    const float* memory = (const float*)d_in[0];
    const float* u      = (const float*)d_in[1];
    const float* embed  = (const float*)d_in[2];
    const float* W_ff   = (const float*)d_in[3];
    const float* b_ff   = (const float*)d_in[4];
    const float* gWih_f = (const float*)d_in[5];
    const float* gWhh_f = (const float*)d_in[6];
    const float* gbih_f = (const float*)d_in[7];
    const float* gbhh_f = (const float*)d_in[8];
    const float* gWih_b = (const float*)d_in[9];
    const float* gWhh_b = (const float*)d_in[10];
    const float* gbih_b = (const float*)d_in[11];
    const float* gbhh_b = (const float*)d_in[12];
    const float* W_k    = (const float*)d_in[13];
    const float* b_k    = (const float*)d_in[14];
    const float* lWih_f = (const float*)d_in[15];
    const float* lWhh_f = (const float*)d_in[16];
    const float* lbih_f = (const float*)d_in[17];
    const float* lbhh_f = (const float*)d_in[18];
    const float* lWih_b = (const float*)d_in[19];
    const float* lWhh_b = (const float*)d_in[20];
    const float* lbih_b = (const float*)d_in[21];
    const float* lbhh_b = (const float*)d_in[22];
    const float* W_out  = (const float*)d_in[23];
    const float* b_out  = (const float*)d_in[24];
    float* out = (float*)d_out;
    float* ws = (float*)d_ws;

    float* dots = ws + OFF_DOTS;
    float* p    = ws + OFF_P;
    float* Mbar = ws + OFF_MBAR;
    float* G    = ws + OFF_G;
    float* giG  = ws + OFF_GIG;
    float* hbuf = ws + OFF_HBUF;
    float* x    = ws + OFF_X;
    float* giL  = ws + OFF_GIL;
    float* comb = ws + OFF_COMB;

    k_dots<<<MM, 256, 0, stream>>>(memory, u, dots);
    k_softmax_p<<<1, MM, 0, stream>>>(dots, p);
    k_wsum<<<128, 128, 0, stream>>>(memory, p, Mbar);
    k_G<<<TT, DD, 0, stream>>>(Mbar, u, W_ff, b_ff, G);
    k_gru_gi<<<TT, 384, 0, stream>>>(G, gWih_f, gbih_f, gWih_b, gbih_b, giG);
    k_gru_seq<<<2, 256, 0, stream>>>(gWhh_f, gbhh_f, gWhh_b, gbhh_b, giG, hbuf);
    k_x<<<TT, EE, 0, stream>>>(u, hbuf, W_k, b_k, embed, x);
    k_lstm_gi<<<dim3(64, 2), 1024, 0, stream>>>(x, lWih_f, lbih_f, lWih_b, lbih_b, giL);
    k_lstm_seq<<<2, 512, 0, stream>>>(lWhh_f, lbhh_f, lWhh_b, lbhh_b, giL, comb);
    k_out<<<TT, 128, 0, stream>>>(comb, W_out, b_out, out);
}

// Round 6
// 1303.761 us; speedup vs baseline: 1.4523x; 1.4523x over previous
//
#include <hip/hip_runtime.h>
#include <math.h>

#define TT 512
#define DD 128
#define MM 512
#define EE 512
#define NTAGS 74
#define GH 64
#define LH 256

typedef _Float16 half_t;
typedef _Float16 v2h __attribute__((ext_vector_type(2)));
typedef _Float16 v8h __attribute__((ext_vector_type(8)));
typedef _Float16 v16h __attribute__((ext_vector_type(16)));
typedef int v4i __attribute__((ext_vector_type(4)));

__device__ __forceinline__ float fdot2f(v2h a, v2h b, float c) {
#if __has_builtin(__builtin_amdgcn_fdot2)
    return __builtin_amdgcn_fdot2(a, b, c, false);
#else
    return c + (float)a[0] * (float)b[0] + (float)a[1] * (float)b[1];
#endif
}

__device__ __forceinline__ int sdot4(int a, int b, int c) {
#if __has_builtin(__builtin_amdgcn_sdot4)
    return __builtin_amdgcn_sdot4(a, b, c, false);
#else
    return c + ((a << 24) >> 24) * ((b << 24) >> 24)
             + ((a << 16) >> 24) * ((b << 16) >> 24)
             + ((a << 8) >> 24) * ((b << 8) >> 24)
             + (a >> 24) * (b >> 24);
#endif
}

__device__ __forceinline__ float sigf(float x) { return 1.f / (1.f + __expf(-x)); }
__device__ __forceinline__ float tanhfast(float x) { return 1.f - 2.f / (__expf(2.f * x) + 1.f); }

// 16 f32 -> v16h (SSA value, 8 VGPRs)
__device__ __forceinline__ v16h load16(const float* p) {
    float4 x0 = ((const float4*)p)[0];
    float4 x1 = ((const float4*)p)[1];
    float4 x2 = ((const float4*)p)[2];
    float4 x3 = ((const float4*)p)[3];
    v16h r;
    r[0] = (half_t)x0.x; r[1] = (half_t)x0.y; r[2] = (half_t)x0.z; r[3] = (half_t)x0.w;
    r[4] = (half_t)x1.x; r[5] = (half_t)x1.y; r[6] = (half_t)x1.z; r[7] = (half_t)x1.w;
    r[8] = (half_t)x2.x; r[9] = (half_t)x2.y; r[10] = (half_t)x2.z; r[11] = (half_t)x2.w;
    r[12] = (half_t)x3.x; r[13] = (half_t)x3.y; r[14] = (half_t)x3.z; r[15] = (half_t)x3.w;
    return r;
}

#define OPAQUE4(a, b, c, d) \
    asm volatile("" : "+v"(a), "+v"(b), "+v"(c), "+v"(d))
#define OPAQUE6(a, b, c, d, e, f) \
    asm volatile("" : "+v"(a), "+v"(b), "+v"(c), "+v"(d), "+v"(e), "+v"(f))

__device__ __forceinline__ void dot16(const v16h& w, const v8h& h0, const v8h& h1,
                                      float& x0, float& x1) {
    x0 = fdot2f(v2h{w[0], w[1]}, v2h{h0[0], h0[1]}, x0);
    x1 = fdot2f(v2h{w[2], w[3]}, v2h{h0[2], h0[3]}, x1);
    x0 = fdot2f(v2h{w[4], w[5]}, v2h{h0[4], h0[5]}, x0);
    x1 = fdot2f(v2h{w[6], w[7]}, v2h{h0[6], h0[7]}, x1);
    x0 = fdot2f(v2h{w[8], w[9]}, v2h{h1[0], h1[1]}, x0);
    x1 = fdot2f(v2h{w[10], w[11]}, v2h{h1[2], h1[3]}, x1);
    x0 = fdot2f(v2h{w[12], w[13]}, v2h{h1[4], h1[5]}, x0);
    x1 = fdot2f(v2h{w[14], w[15]}, v2h{h1[6], h1[7]}, x1);
}

__device__ __forceinline__ int pack4(int b0, int b1, int b2, int b3) {
    return (b0 & 0xff) | ((b1 & 0xff) << 8) | ((b2 & 0xff) << 16) | (b3 << 24);
}

// quantize 16 consecutive f32 weights -> 16 int8 packed in v4i
__device__ __forceinline__ v4i quant16(const float* p, float inv_s) {
    float4 x0 = ((const float4*)p)[0];
    float4 x1 = ((const float4*)p)[1];
    float4 x2 = ((const float4*)p)[2];
    float4 x3 = ((const float4*)p)[3];
    v4i r;
    r.x = pack4(__float2int_rn(x0.x * inv_s), __float2int_rn(x0.y * inv_s),
                __float2int_rn(x0.z * inv_s), __float2int_rn(x0.w * inv_s));
    r.y = pack4(__float2int_rn(x1.x * inv_s), __float2int_rn(x1.y * inv_s),
                __float2int_rn(x1.z * inv_s), __float2int_rn(x1.w * inv_s));
    r.z = pack4(__float2int_rn(x2.x * inv_s), __float2int_rn(x2.y * inv_s),
                __float2int_rn(x2.z * inv_s), __float2int_rn(x2.w * inv_s));
    r.w = pack4(__float2int_rn(x3.x * inv_s), __float2int_rn(x3.y * inv_s),
                __float2int_rn(x3.z * inv_s), __float2int_rn(x3.w * inv_s));
    return r;
}

// ---------------- K1: dots[m] = <memory[m], u> ----------------
__global__ __launch_bounds__(256) void k_dots(const float* __restrict__ mem,
                                              const float* __restrict__ u,
                                              float* __restrict__ dots) {
    int m = blockIdx.x;
    const float4* m4 = (const float4*)(mem + (size_t)m * TT * DD);
    const float4* u4 = (const float4*)u;
    float acc = 0.f;
#pragma unroll 4
    for (int it = 0; it < (TT * DD / 4) / 256; ++it) {
        int i = it * 256 + threadIdx.x;
        float4 a = m4[i], b = u4[i];
        acc += a.x * b.x + a.y * b.y + a.z * b.z + a.w * b.w;
    }
    for (int off = 32; off; off >>= 1) acc += __shfl_down(acc, off, 64);
    __shared__ float red[4];
    int w = threadIdx.x >> 6, l = threadIdx.x & 63;
    if (l == 0) red[w] = acc;
    __syncthreads();
    if (threadIdx.x == 0) dots[m] = red[0] + red[1] + red[2] + red[3];
}

// ---------------- K2: p = softmax(dots) ----------------
__global__ __launch_bounds__(512) void k_softmax_p(const float* __restrict__ dots,
                                                   float* __restrict__ p) {
    int tid = threadIdx.x;
    float v = dots[tid];
    float mx = v;
    for (int off = 32; off; off >>= 1) mx = fmaxf(mx, __shfl_down(mx, off, 64));
    __shared__ float red[8];
    __shared__ float bm, bs;
    int w = tid >> 6, l = tid & 63;
    if (l == 0) red[w] = mx;
    __syncthreads();
    if (tid == 0) {
        float t = red[0];
        for (int i = 1; i < 8; ++i) t = fmaxf(t, red[i]);
        bm = t;
    }
    __syncthreads();
    float e = __expf(v - bm);
    float sm = e;
    for (int off = 32; off; off >>= 1) sm += __shfl_down(sm, off, 64);
    if (l == 0) red[w] = sm;
    __syncthreads();
    if (tid == 0) {
        float t = 0.f;
        for (int i = 0; i < 8; ++i) t += red[i];
        bs = t;
    }
    __syncthreads();
    p[tid] = e / bs;
}

// ---------------- K3: Mbar = sum_m p[m]*memory[m] ----------------
__global__ __launch_bounds__(128) void k_wsum(const float* __restrict__ mem,
                                              const float* __restrict__ p,
                                              float* __restrict__ Mbar) {
    __shared__ float pl[MM];
    for (int i = threadIdx.x; i < MM; i += 128) pl[i] = p[i];
    __syncthreads();
    int i4 = blockIdx.x * 128 + threadIdx.x;
    const float4* m4 = (const float4*)mem;
    float4 acc = {0.f, 0.f, 0.f, 0.f};
#pragma unroll 4
    for (int m = 0; m < MM; ++m) {
        float pm = pl[m];
        float4 a = m4[(size_t)m * (TT * DD / 4) + i4];
        acc.x += pm * a.x; acc.y += pm * a.y; acc.z += pm * a.z; acc.w += pm * a.w;
    }
    ((float4*)Mbar)[i4] = acc;
}

// ---------------- K4: G = Mbar@W1.T + u@W2.T + b_ff ----------------
__global__ __launch_bounds__(128) void k_G(const float* __restrict__ Mbar,
                                           const float* __restrict__ u,
                                           const float* __restrict__ Wff,
                                           const float* __restrict__ bff,
                                           float* __restrict__ G) {
    int t = blockIdx.x, d = threadIdx.x;
    __shared__ __align__(16) float Ml[DD], ul[DD];
    Ml[d] = Mbar[t * DD + d];
    ul[d] = u[t * DD + d];
    __syncthreads();
    const float* wr = Wff + (size_t)d * 2 * DD;
    float a0 = 0.f, a1 = 0.f;
#pragma unroll 4
    for (int k = 0; k < DD; ++k) {
        a0 += Ml[k] * wr[k];
        a1 += ul[k] * wr[DD + k];
    }
    G[t * DD + d] = a0 + a1 + bff[d];
}

// ---------------- K5: GRU input projections ----------------
__global__ __launch_bounds__(384) void k_gru_gi(const float* __restrict__ G,
                                                const float* __restrict__ Wf,
                                                const float* __restrict__ bf,
                                                const float* __restrict__ Wb,
                                                const float* __restrict__ bb,
                                                float* __restrict__ gi) {
    int t = blockIdx.x;
    __shared__ __align__(16) float Gl[DD];
    if (threadIdx.x < DD) Gl[threadIdx.x] = G[t * DD + threadIdx.x];
    __syncthreads();
    int r = threadIdx.x;
    const float* w;
    float b;
    float* o;
    if (r < 192) {
        w = Wf + (size_t)r * DD; b = bf[r]; o = gi + ((size_t)0 * TT + t) * 192 + r;
    } else {
        int rr = r - 192;
        w = Wb + (size_t)rr * DD; b = bb[rr]; o = gi + ((size_t)1 * TT + t) * 192 + rr;
    }
    float a0 = 0.f, a1 = 0.f;
#pragma unroll 4
    for (int k = 0; k < DD; k += 2) {
        a0 += Gl[k] * w[k];
        a1 += Gl[k + 1] * w[k + 1];
    }
    *o = a0 + a1 + b;
}

// ---------------- K6: sequential BiGRU (2 blocks = 2 directions) ----------------
__global__ __launch_bounds__(256) void k_gru_seq(const float* __restrict__ Whh_f,
                                                 const float* __restrict__ bhh_f,
                                                 const float* __restrict__ Whh_b,
                                                 const float* __restrict__ bhh_b,
                                                 const float* __restrict__ gi,
                                                 float* __restrict__ hbuf) {
    int dir = blockIdx.x;
    int tid = threadIdx.x;
    const float* Whh = dir ? Whh_b : Whh_f;
    const float* bhh = dir ? bhh_b : bhh_f;
    v16h w0 = {}, w1 = {}, w2 = {}, w3 = {};
    float bh = 0.f;
    if (tid < 192) {
        const float* wr = Whh + (size_t)tid * 64;
        w0 = load16(wr);
        w1 = load16(wr + 16);
        w2 = load16(wr + 32);
        w3 = load16(wr + 48);
        bh = bhh[tid];
    }
    OPAQUE4(w0, w1, w2, w3);
    __shared__ __align__(16) half_t hl[64];
    __shared__ float pa[192];
    if (tid < 32) ((v2h*)hl)[tid] = v2h{(half_t)0.f, (half_t)0.f};
    float h = 0.f;
    __syncthreads();
    for (int s = 0; s < TT; ++s) {
        int t = dir ? (TT - 1 - s) : s;
        float g_r = 0.f, g_z = 0.f, g_n = 0.f;
        if (tid < 64) {  // prefetch gi early
            const float* git = gi + ((size_t)dir * TT + t) * 192;
            g_r = git[tid]; g_z = git[64 + tid]; g_n = git[128 + tid];
        }
        if (tid < 192) {
            float a0 = bh, a1 = 0.f;
            v8h h0, h1;
            h0 = *(const v8h*)(hl + 0);  h1 = *(const v8h*)(hl + 8);
            dot16(w0, h0, h1, a0, a1);
            h0 = *(const v8h*)(hl + 16); h1 = *(const v8h*)(hl + 24);
            dot16(w1, h0, h1, a0, a1);
            h0 = *(const v8h*)(hl + 32); h1 = *(const v8h*)(hl + 40);
            dot16(w2, h0, h1, a0, a1);
            h0 = *(const v8h*)(hl + 48); h1 = *(const v8h*)(hl + 56);
            dot16(w3, h0, h1, a0, a1);
            pa[tid] = a0 + a1;
        }
        __syncthreads();
        if (tid < 64) {
            float r = sigf(g_r + pa[tid]);
            float z = sigf(g_z + pa[64 + tid]);
            float n = tanhfast(g_n + r * pa[128 + tid]);
            h = (1.f - z) * n + z * h;
            hbuf[t * DD + dir * 64 + tid] = h;
            hl[tid] = (half_t)h;
        }
        __syncthreads();
    }
}

// ---------------- K7: x = embed + (u + h)@W_k.T + b_k ----------------
__global__ __launch_bounds__(512) void k_x(const float* __restrict__ u,
                                           const float* __restrict__ hbuf,
                                           const float* __restrict__ Wk,
                                           const float* __restrict__ bk,
                                           const float* __restrict__ embed,
                                           float* __restrict__ x) {
    int t = blockIdx.x, e = threadIdx.x;
    __shared__ __align__(16) float sl[DD];
    if (e < DD) sl[e] = u[t * DD + e] + hbuf[t * DD + e];
    __syncthreads();
    const float* wr = Wk + (size_t)e * DD;
    float a0 = 0.f, a1 = 0.f;
#pragma unroll 4
    for (int k = 0; k < DD; k += 2) {
        a0 += sl[k] * wr[k];
        a1 += sl[k + 1] * wr[k + 1];
    }
    x[t * EE + e] = embed[t * EE + e] + a0 + a1 + bk[e];
}

// ---------------- K8: LSTM input projections, 8 timesteps per block ----------------
__global__ __launch_bounds__(1024) void k_lstm_gi(const float* __restrict__ x,
                                                  const float* __restrict__ Wf,
                                                  const float* __restrict__ bf,
                                                  const float* __restrict__ Wb,
                                                  const float* __restrict__ bb,
                                                  float* __restrict__ gi) {
    int dir = blockIdx.y;
    int t0 = blockIdx.x * 8;
    __shared__ __align__(16) float xl[8 * EE];
    for (int i = threadIdx.x; i < 8 * EE; i += 1024) xl[i] = x[(size_t)t0 * EE + i];
    __syncthreads();
    int r = threadIdx.x;
    const float* W = dir ? Wb : Wf;
    const float* bi = dir ? bb : bf;
    const float* wr = W + (size_t)r * EE;
    float b = bi[r];
    float acc[8];
#pragma unroll
    for (int uu = 0; uu < 8; ++uu) acc[uu] = b;
    for (int k = 0; k < EE; k += 4) {
        float4 wv = *(const float4*)(wr + k);
#pragma unroll
        for (int uu = 0; uu < 8; ++uu) {
            float4 xv = *(const float4*)(&xl[uu * EE + k]);
            acc[uu] += wv.x * xv.x + wv.y * xv.y + wv.z * xv.z + wv.w * xv.w;
        }
    }
#pragma unroll
    for (int uu = 0; uu < 8; ++uu)
        gi[((size_t)dir * TT + (t0 + uu)) * 1024 + r] = acc[uu];
}

// ---------------- K9: sequential BiLSTM, one WG per direction ----------------
// int8 path: per-row symmetric quant (scale rowmax/127), exact i32 sdot4
// accumulation, one float rescale. 512 threads x 2 rows; cols 0..191 as
// 24 named v4i = 96 VGPRs (+~24 working = 120 <= the allocator's observed
// 128 target -> NO spill, unlike f16 which needs 192+); cols 192..255 as
// int8 in LDS (64 KB). h requantized to int8 each step (|h|<1 exactly).
// gi/bias/gates stay f32 -- only the small recurrent term is quantized.
__global__ __launch_bounds__(512) void k_lstm_seq(const float* __restrict__ Whh_f,
                                                  const float* __restrict__ bhh_f,
                                                  const float* __restrict__ Whh_b,
                                                  const float* __restrict__ bhh_b,
                                                  const float* __restrict__ gi,
                                                  float* __restrict__ comb) {
    int dir = blockIdx.x;
    int tid = threadIdx.x;
    int u = tid & 255;
    int hi = tid >> 8;               // 0 -> rows (i,g); 1 -> rows (f,o)
    int r0 = hi * 256 + u;           // gate i or f
    int r1 = 512 + hi * 256 + u;     // gate g or o
    const float* Whh = dir ? Whh_b : Whh_f;
    const float* bhh = dir ? bhh_b : bhh_f;

    __shared__ __align__(16) int wsl[4][1024][4];  // [chunk][row][16 int8] = 64 KB
    __shared__ __align__(16) int hq[64];           // 256 int8 = current h
    __shared__ float pa[1024];

    const float* s0 = Whh + (size_t)r0 * 256;
    const float* s1 = Whh + (size_t)r1 * 256;
    // per-row scales
    float mx0 = 0.f, mx1 = 0.f;
    for (int k = 0; k < 256; k += 4) {
        float4 a = *(const float4*)(s0 + k);
        float4 b = *(const float4*)(s1 + k);
        mx0 = fmaxf(mx0, fmaxf(fmaxf(fabsf(a.x), fabsf(a.y)), fmaxf(fabsf(a.z), fabsf(a.w))));
        mx1 = fmaxf(mx1, fmaxf(fmaxf(fabsf(b.x), fabsf(b.y)), fmaxf(fabsf(b.z), fabsf(b.w))));
    }
    float inv0 = 127.f / mx0, inv1 = 127.f / mx1;
    float fs0 = mx0 / 16129.f, fs1 = mx1 / 16129.f;  // mx/(127*127)

    // LDS weight slice: cols 192..255 of own rows.
#pragma unroll
    for (int cc = 0; cc < 4; ++cc) {
        *(v4i*)&wsl[cc][r0][0] = quant16(s0 + 192 + 16 * cc, inv0);
        *(v4i*)&wsl[cc][r1][0] = quant16(s1 + 192 + 16 * cc, inv1);
    }
    // Register weights: cols 0..191 of both rows.
    v4i wa0 = quant16(s0, inv0),        wa1 = quant16(s0 + 16, inv0),
        wa2 = quant16(s0 + 32, inv0),   wa3 = quant16(s0 + 48, inv0),
        wa4 = quant16(s0 + 64, inv0),   wa5 = quant16(s0 + 80, inv0),
        wa6 = quant16(s0 + 96, inv0),   wa7 = quant16(s0 + 112, inv0),
        wa8 = quant16(s0 + 128, inv0),  wa9 = quant16(s0 + 144, inv0),
        wa10 = quant16(s0 + 160, inv0), wa11 = quant16(s0 + 176, inv0);
    v4i wb0 = quant16(s1, inv1),        wb1 = quant16(s1 + 16, inv1),
        wb2 = quant16(s1 + 32, inv1),   wb3 = quant16(s1 + 48, inv1),
        wb4 = quant16(s1 + 64, inv1),   wb5 = quant16(s1 + 80, inv1),
        wb6 = quant16(s1 + 96, inv1),   wb7 = quant16(s1 + 112, inv1),
        wb8 = quant16(s1 + 128, inv1),  wb9 = quant16(s1 + 144, inv1),
        wb10 = quant16(s1 + 160, inv1), wb11 = quant16(s1 + 176, inv1);
    OPAQUE6(wa0, wa1, wa2, wa3, wa4, wa5);
    OPAQUE6(wa6, wa7, wa8, wa9, wa10, wa11);
    OPAQUE6(wb0, wb1, wb2, wb3, wb4, wb5);
    OPAQUE6(wb6, wb7, wb8, wb9, wb10, wb11);
    float bh0 = bhh[r0], bh1 = bhh[r1];
    if (tid < 64) hq[tid] = 0;
    float c_state = 0.f;
    __syncthreads();

    for (int s = 0; s < TT; ++s) {
        int t = dir ? (TT - 1 - s) : s;
        const float* gbase = gi + ((size_t)dir * TT + t) * 1024;
        float g0v = gbase[r0], g1v = gbase[r1];
        int a0 = 0, a1 = 0, b0 = 0, b1 = 0;
        const v4i* h4 = (const v4i*)hq;
#define DOTC(c) { v4i h = h4[c];                                     \
        a0 = sdot4(wa##c.x, h.x, a0); a1 = sdot4(wa##c.y, h.y, a1);  \
        a0 = sdot4(wa##c.z, h.z, a0); a1 = sdot4(wa##c.w, h.w, a1);  \
        b0 = sdot4(wb##c.x, h.x, b0); b1 = sdot4(wb##c.y, h.y, b1);  \
        b0 = sdot4(wb##c.z, h.z, b0); b1 = sdot4(wb##c.w, h.w, b1); }
        DOTC(0); DOTC(1); DOTC(2); DOTC(3); DOTC(4); DOTC(5);
        DOTC(6); DOTC(7); DOTC(8); DOTC(9); DOTC(10); DOTC(11);
#undef DOTC
        // LDS-resident cols 192..255 (h chunks 12..15).
#pragma unroll
        for (int cc = 0; cc < 4; ++cc) {
            v4i h = h4[12 + cc];
            v4i va = *(const v4i*)&wsl[cc][r0][0];
            v4i vb = *(const v4i*)&wsl[cc][r1][0];
            a0 = sdot4(va.x, h.x, a0); a1 = sdot4(va.y, h.y, a1);
            a0 = sdot4(va.z, h.z, a0); a1 = sdot4(va.w, h.w, a1);
            b0 = sdot4(vb.x, h.x, b0); b1 = sdot4(vb.y, h.y, b1);
            b0 = sdot4(vb.z, h.z, b0); b1 = sdot4(vb.w, h.w, b1);
        }
        pa[r0] = (float)(a0 + a1) * fs0 + bh0 + g0v;
        pa[r1] = (float)(b0 + b1) * fs1 + bh1 + g1v;
        __syncthreads();
        if (tid < 256) {
            float iv = sigf(pa[tid]);
            float fv = sigf(pa[256 + tid]);
            float gv = tanhfast(pa[512 + tid]);
            float ov = sigf(pa[768 + tid]);
            c_state = fv * c_state + iv * gv;
            float h = ov * tanhfast(c_state);
            comb[(size_t)t * EE + dir * 256 + tid] = h;
            ((signed char*)hq)[tid] = (signed char)__float2int_rn(h * 127.f);
        }
        __syncthreads();
    }
}

// ---------------- K10: logits + softmax ----------------
__global__ __launch_bounds__(128) void k_out(const float* __restrict__ comb,
                                             const float* __restrict__ Wout,
                                             const float* __restrict__ bout,
                                             float* __restrict__ out) {
    int t = blockIdx.x;
    __shared__ __align__(16) float cl[EE];
    __shared__ float ll[NTAGS];
    __shared__ float mred, sred;
    for (int i = threadIdx.x; i < EE; i += 128) cl[i] = comb[(size_t)t * EE + i];
    __syncthreads();
    int e = threadIdx.x;
    if (e < NTAGS) {
        const float* wr = Wout + (size_t)e * EE;
        float a0 = 0.f, a1 = 0.f;
#pragma unroll 4
        for (int k = 0; k < EE; k += 2) {
            a0 += cl[k] * wr[k];
            a1 += cl[k + 1] * wr[k + 1];
        }
        ll[e] = a0 + a1 + bout[e];
    }
    __syncthreads();
    if (threadIdx.x == 0) {
        float m = ll[0];
        for (int i = 1; i < NTAGS; ++i) m = fmaxf(m, ll[i]);
        float ss = 0.f;
        for (int i = 0; i < NTAGS; ++i) ss += __expf(ll[i] - m);
        mred = m;
        sred = ss;
    }
    __syncthreads();
    if (e < NTAGS) out[t * NTAGS + e] = __expf(ll[e] - mred) / sred;
}

// ---------------- workspace layout (floats) ----------------
#define OFF_DOTS  ((size_t)0)
#define OFF_P     ((size_t)512)
#define OFF_MBAR  ((size_t)1024)
#define OFF_G     ((size_t)66560)
#define OFF_GIG   ((size_t)132096)   // [2][512][192]
#define OFF_HBUF  ((size_t)328704)   // [512][128]
#define OFF_X     ((size_t)394240)   // [512][512]
#define OFF_GIL   ((size_t)656384)   // [2][512][1024]
#define OFF_COMB  ((size_t)1704960)  // [512][512]

extern "C" void kernel_launch(void* const* d_in, const int* in_sizes, int n_in,
                              void* d_out, int out_size, void* d_ws, size_t ws_size,
                              hipStream_t stream) {
    const float* memory = (const float*)d_in[0];
    const float* u      = (const float*)d_in[1];
    const float* embed  = (const float*)d_in[2];
    const float* W_ff   = (const float*)d_in[3];
    const float* b_ff   = (const float*)d_in[4];
    const float* gWih_f = (const float*)d_in[5];
    const float* gWhh_f = (const float*)d_in[6];
    const float* gbih_f = (const float*)d_in[7];
    const float* gbhh_f = (const float*)d_in[8];
    const float* gWih_b = (const float*)d_in[9];
    const float* gWhh_b = (const float*)d_in[10];
    const float* gbih_b = (const float*)d_in[11];
    const float* gbhh_b = (const float*)d_in[12];
    const float* W_k    = (const float*)d_in[13];
    const float* b_k    = (const float*)d_in[14];
    const float* lWih_f = (const float*)d_in[15];
    const float* lWhh_f = (const float*)d_in[16];
    const float* lbih_f = (const float*)d_in[17];
    const float* lbhh_f = (const float*)d_in[18];
    const float* lWih_b = (const float*)d_in[19];
    const float* lWhh_b = (const float*)d_in[20];
    const float* lbih_b = (const float*)d_in[21];
    const float* lbhh_b = (const float*)d_in[22];
    const float* W_out  = (const float*)d_in[23];
    const float* b_out  = (const float*)d_in[24];
    float* out = (float*)d_out;
    float* ws = (float*)d_ws;

    float* dots = ws + OFF_DOTS;
    float* p    = ws + OFF_P;
    float* Mbar = ws + OFF_MBAR;
    float* G    = ws + OFF_G;
    float* giG  = ws + OFF_GIG;
    float* hbuf = ws + OFF_HBUF;
    float* x    = ws + OFF_X;
    float* giL  = ws + OFF_GIL;
    float* comb = ws + OFF_COMB;

    k_dots<<<MM, 256, 0, stream>>>(memory, u, dots);
    k_softmax_p<<<1, MM, 0, stream>>>(dots, p);
    k_wsum<<<128, 128, 0, stream>>>(memory, p, Mbar);
    k_G<<<TT, DD, 0, stream>>>(Mbar, u, W_ff, b_ff, G);
    k_gru_gi<<<TT, 384, 0, stream>>>(G, gWih_f, gbih_f, gWih_b, gbih_b, giG);
    k_gru_seq<<<2, 256, 0, stream>>>(gWhh_f, gbhh_f, gWhh_b, gbhh_b, giG, hbuf);
    k_x<<<TT, EE, 0, stream>>>(u, hbuf, W_k, b_k, embed, x);
    k_lstm_gi<<<dim3(64, 2), 1024, 0, stream>>>(x, lWih_f, lbih_f, lWih_b, lbih_b, giL);
    k_lstm_seq<<<2, 512, 0, stream>>>(lWhh_f, lbhh_f, lWhh_b, lbhh_b, giL, comb);
    k_out<<<TT, 128, 0, stream>>>(comb, W_out, b_out, out);
}